// Round 1
// baseline (249.261 us; speedup 1.0000x reference)
//
#include <hip/hip_runtime.h>

constexpr int N       = 50000;
constexpr int NE      = 800000;
constexpr int AD      = 128;   // ATOM_DIM
constexpr int BD      = 16;    // BOND_DIM
constexpr int BD2     = 256;   // BD*BD
constexpr int HIDDEN  = 128;
constexpr int NB      = 64;    // nodes per block in fused kernel

// ---------------------------------------------------------------------------
// Kernel 1: S[s] = sum over edges with src==s of bonds[nbr]
// thread = (edge, component); bonds reads coalesced per 16-lane group.
// ---------------------------------------------------------------------------
__global__ __launch_bounds__(256) void edge_scatter(
    const int* __restrict__ pairs,
    const float* __restrict__ bonds,
    float* __restrict__ S)
{
    const long total  = (long)NE * BD;
    const long stride = (long)gridDim.x * blockDim.x;
    for (long t = (long)blockIdx.x * blockDim.x + threadIdx.x; t < total; t += stride) {
        int e = (int)(t >> 4);
        int c = (int)(t & 15);
        int src = pairs[2 * e];
        int nbr = pairs[2 * e + 1];
        atomicAdd(&S[src * BD + c], bonds[nbr * BD + c]);
    }
}

// ---------------------------------------------------------------------------
// Kernel 2: fused per-node pipeline.
//  A[n] = atoms[n] @ kmat + bias          (1x256, reshaped 16x16)
//  agg[n] = A[n] . S[n]                   (16)
//  out = relu(agg@Wn + relu(bonds[n]@Wi)) (128), written 4x
// Block: 256 threads, 64 nodes. GEMM register blocking: 8 rows x 8 cols.
// ---------------------------------------------------------------------------
__device__ inline float4 f4zero() { return make_float4(0.f, 0.f, 0.f, 0.f); }

__global__ __launch_bounds__(256) void fused_node(
    const float* __restrict__ atoms,
    const float* __restrict__ bonds,
    const float* __restrict__ kmat,   // 128 x 256
    const float* __restrict__ bias,   // 256
    const float* __restrict__ Wn,     // 16 x 128
    const float* __restrict__ Wi,     // 16 x 128
    const float* __restrict__ S,      // N x 16
    float* __restrict__ out)          // 4 x N x 128
{
    __shared__ float k_lds[16 * 256];     // 16KB  kernel K-chunk
    __shared__ float atoms_t[16 * 64];    // 4KB   atoms chunk, transposed [k][row]
    __shared__ float s_lds[NB * 16];      // 4KB
    __shared__ float bonds_lds[NB * 16];  // 4KB
    __shared__ float agg_lds[NB * 17];    // padded stride 17
    __shared__ float wn_lds[16 * 128];    // 8KB
    __shared__ float wi_lds[16 * 128];    // 8KB

    const int tid = threadIdx.x;
    const int nb  = blockIdx.x * NB;

    // ---- persistent staging: S, bonds, Wn, Wi -----------------------------
    {
        int row = tid >> 2;
        int j4  = (tid & 3) * 4;
        int n   = nb + row;
        float4 sv = f4zero(), bv = f4zero();
        if (n < N) {
            sv = *(const float4*)(S + n * BD + j4);
            bv = *(const float4*)(bonds + n * BD + j4);
        }
        *(float4*)(s_lds + row * 16 + j4)     = sv;
        *(float4*)(bonds_lds + row * 16 + j4) = bv;
#pragma unroll
        for (int p = 0; p < 2; ++p) {
            int idx = tid + 256 * p;
            int r2  = idx >> 5;
            int h4  = (idx & 31) * 4;
            *(float4*)(wn_lds + r2 * 128 + h4) = *(const float4*)(Wn + r2 * 128 + h4);
            *(float4*)(wi_lds + r2 * 128 + h4) = *(const float4*)(Wi + r2 * 128 + h4);
        }
    }

    const int rg = tid >> 5;   // 0..7  -> rows rg*8 .. rg*8+7
    const int cq = tid & 31;   // 0..31 -> float4 cols cq and cq+32

    float4 acc[8][2];
#pragma unroll
    for (int i = 0; i < 8; ++i) { acc[i][0] = f4zero(); acc[i][1] = f4zero(); }

    float4 bias_v0 = *(const float4*)(bias + cq * 4);
    float4 bias_v1 = *(const float4*)(bias + cq * 4 + 128);

    // ---- GEMM: A = atoms @ kmat, K-chunks of 16 ---------------------------
    const int ld_row = tid >> 2;         // staging helpers
    const int ld_k4  = (tid & 3) * 4;

    for (int kk = 0; kk < AD; kk += 16) {
        // load to registers first
        float4 areg = f4zero();
        {
            int n = nb + ld_row;
            if (n < N) areg = *(const float4*)(atoms + (size_t)n * AD + kk + ld_k4);
        }
        float4 kreg[4];
#pragma unroll
        for (int p = 0; p < 4; ++p) {
            int idx  = tid + 256 * p;
            int krow = idx >> 6;
            int kc4  = (idx & 63) * 4;
            kreg[p] = *(const float4*)(kmat + (size_t)(kk + krow) * BD2 + kc4);
        }
        __syncthreads();   // previous chunk fully consumed
        // atoms transposed: atoms_t[k][row]
        atoms_t[(ld_k4 + 0) * 64 + ld_row] = areg.x;
        atoms_t[(ld_k4 + 1) * 64 + ld_row] = areg.y;
        atoms_t[(ld_k4 + 2) * 64 + ld_row] = areg.z;
        atoms_t[(ld_k4 + 3) * 64 + ld_row] = areg.w;
#pragma unroll
        for (int p = 0; p < 4; ++p) {
            int idx  = tid + 256 * p;
            int krow = idx >> 6;
            int kc4  = (idx & 63) * 4;
            *(float4*)(k_lds + krow * 256 + kc4) = kreg[p];
        }
        __syncthreads();

#pragma unroll
        for (int k = 0; k < 16; ++k) {
            float4 a0 = *(const float4*)(atoms_t + k * 64 + rg * 8);
            float4 a1 = *(const float4*)(atoms_t + k * 64 + rg * 8 + 4);
            float4 kv0 = *(const float4*)(k_lds + k * 256 + cq * 4);
            float4 kv1 = *(const float4*)(k_lds + k * 256 + cq * 4 + 128);
            float a[8] = {a0.x, a0.y, a0.z, a0.w, a1.x, a1.y, a1.z, a1.w};
#pragma unroll
            for (int i = 0; i < 8; ++i) {
                acc[i][0].x = fmaf(a[i], kv0.x, acc[i][0].x);
                acc[i][0].y = fmaf(a[i], kv0.y, acc[i][0].y);
                acc[i][0].z = fmaf(a[i], kv0.z, acc[i][0].z);
                acc[i][0].w = fmaf(a[i], kv0.w, acc[i][0].w);
                acc[i][1].x = fmaf(a[i], kv1.x, acc[i][1].x);
                acc[i][1].y = fmaf(a[i], kv1.y, acc[i][1].y);
                acc[i][1].z = fmaf(a[i], kv1.z, acc[i][1].z);
                acc[i][1].w = fmaf(a[i], kv1.w, acc[i][1].w);
            }
        }
    }

    // ---- bias + contract with S, reduce across 4 j-groups via shfl --------
    // thread's columns: col = cq*4 + q*128 + m  -> i = q*8 + (cq>>2), j = (cq&3)*4 + m
    {
        const int jg = (cq & 3) * 4;
        const int ibase = cq >> 2;
#pragma unroll
        for (int r = 0; r < 8; ++r) {
            int row = rg * 8 + r;
            float4 sv = *(const float4*)(s_lds + row * 16 + jg);
#pragma unroll
            for (int q = 0; q < 2; ++q) {
                float4 av = acc[r][q];
                float4 bvq = (q == 0) ? bias_v0 : bias_v1;
                av.x += bvq.x; av.y += bvq.y; av.z += bvq.z; av.w += bvq.w;
                float p = av.x * sv.x + av.y * sv.y + av.z * sv.z + av.w * sv.w;
                p += __shfl_xor(p, 1);
                p += __shfl_xor(p, 2);
                if ((tid & 3) == 0) {
                    agg_lds[row * 17 + q * 8 + ibase] = p;
                }
            }
        }
    }
    __syncthreads();

    // ---- epilogue: out = relu(agg@Wn + relu(bonds@Wi)), 4 copies ----------
    {
        const int r  = tid >> 2;   // node row 0..63
        const int hg = tid & 3;
        const int n  = nb + r;
        float aggv[16], bv[16];
#pragma unroll
        for (int i = 0; i < 16; ++i) {
            aggv[i] = agg_lds[r * 17 + i];
            bv[i]   = bonds_lds[r * 16 + i];
        }
        if (n < N) {
#pragma unroll
            for (int hv = 0; hv < 8; ++hv) {
                int h = (hv * 4 + hg) * 4;
                float4 nv = f4zero(), ev = f4zero();
#pragma unroll
                for (int i = 0; i < 16; ++i) {
                    float4 w  = *(const float4*)(wn_lds + i * 128 + h);
                    float4 w2 = *(const float4*)(wi_lds + i * 128 + h);
                    nv.x = fmaf(aggv[i], w.x, nv.x);
                    nv.y = fmaf(aggv[i], w.y, nv.y);
                    nv.z = fmaf(aggv[i], w.z, nv.z);
                    nv.w = fmaf(aggv[i], w.w, nv.w);
                    ev.x = fmaf(bv[i], w2.x, ev.x);
                    ev.y = fmaf(bv[i], w2.y, ev.y);
                    ev.z = fmaf(bv[i], w2.z, ev.z);
                    ev.w = fmaf(bv[i], w2.w, ev.w);
                }
                ev.x = fmaxf(ev.x, 0.f); ev.y = fmaxf(ev.y, 0.f);
                ev.z = fmaxf(ev.z, 0.f); ev.w = fmaxf(ev.w, 0.f);
                float4 rv;
                rv.x = fmaxf(nv.x + ev.x, 0.f);
                rv.y = fmaxf(nv.y + ev.y, 0.f);
                rv.z = fmaxf(nv.z + ev.z, 0.f);
                rv.w = fmaxf(nv.w + ev.w, 0.f);
#pragma unroll
                for (int s = 0; s < 4; ++s) {
                    *(float4*)(out + ((size_t)s * N + n) * HIDDEN + h) = rv;
                }
            }
        }
    }
}

// ---------------------------------------------------------------------------
extern "C" void kernel_launch(void* const* d_in, const int* in_sizes, int n_in,
                              void* d_out, int out_size, void* d_ws, size_t ws_size,
                              hipStream_t stream)
{
    const float* atoms = (const float*)d_in[0];
    const float* bonds = (const float*)d_in[1];
    const int*   pairs = (const int*)d_in[2];
    const float* kmat  = (const float*)d_in[3];
    const float* bias  = (const float*)d_in[4];
    const float* Wn    = (const float*)d_in[5];
    const float* Wi    = (const float*)d_in[6];
    float* out = (float*)d_out;
    float* S   = (float*)d_ws;   // N x 16

    hipMemsetAsync(S, 0, (size_t)N * BD * sizeof(float), stream);
    edge_scatter<<<4096, 256, 0, stream>>>(pairs, bonds, S);
    fused_node<<<(N + NB - 1) / NB, 256, 0, stream>>>(
        atoms, bonds, kmat, bias, Wn, Wi, S, out);
}

// Round 2
// 119.210 us; speedup vs baseline: 2.0909x; 2.0909x over previous
//
#include <hip/hip_runtime.h>

constexpr int N       = 50000;
constexpr int NE      = 800000;
constexpr int AD      = 128;   // ATOM_DIM
constexpr int BD      = 16;    // BOND_DIM
constexpr int BD2     = 256;   // BD*BD
constexpr int HIDDEN  = 128;
constexpr int NB      = 64;    // nodes per block in fused kernel
constexpr int EPG     = 32;    // edges per 16-lane group in scatter

// ---------------------------------------------------------------------------
// Kernel 1: S[s] = sum over edges with src==s of bonds[nbr]
// pairs are sorted by src -> run-length segmented reduction.
// 16-lane group owns EPG consecutive edges, one component per lane;
// accumulate in register, atomicAdd only at run boundaries.
// ---------------------------------------------------------------------------
__global__ __launch_bounds__(256) void edge_scatter_sorted(
    const int2* __restrict__ pairs,
    const float* __restrict__ bonds,
    float* __restrict__ S)
{
    const int gid = (int)((blockIdx.x * (unsigned)blockDim.x + threadIdx.x) >> 4);
    const int c   = threadIdx.x & 15;
    long e0 = (long)gid * EPG;
    if (e0 >= NE) return;
    long e1 = e0 + EPG;
    if (e1 > NE) e1 = NE;

    int2 p0 = pairs[e0];
    int   cur = p0.x;
    float acc = bonds[(size_t)p0.y * BD + c];

    for (long e = e0 + 1; e < e1; ++e) {
        int2 p = pairs[e];
        float v = bonds[(size_t)p.y * BD + c];
        if (p.x != cur) {
            atomicAdd(&S[(size_t)cur * BD + c], acc);
            acc = 0.f;
            cur = p.x;
        }
        acc += v;
    }
    atomicAdd(&S[(size_t)cur * BD + c], acc);
}

// ---------------------------------------------------------------------------
// Kernel 2: fused per-node pipeline.
//  A[n] = atoms[n] @ kmat + bias          (1x256, reshaped 16x16)
//  agg[n] = A[n] . S[n]                   (16)
//  out = relu(agg@Wn + relu(bonds[n]@Wi)) (128), written 4x
// Block: 256 threads, 64 nodes. GEMM register blocking: 8 rows x 8 cols.
// ---------------------------------------------------------------------------
__device__ inline float4 f4zero() { return make_float4(0.f, 0.f, 0.f, 0.f); }

__global__ __launch_bounds__(256) void fused_node(
    const float* __restrict__ atoms,
    const float* __restrict__ bonds,
    const float* __restrict__ kmat,   // 128 x 256
    const float* __restrict__ bias,   // 256
    const float* __restrict__ Wn,     // 16 x 128
    const float* __restrict__ Wi,     // 16 x 128
    const float* __restrict__ S,      // N x 16
    float* __restrict__ out)          // 4 x N x 128
{
    __shared__ float k_lds[16 * 256];     // 16KB  kernel K-chunk
    __shared__ float atoms_t[16 * 64];    // 4KB   atoms chunk, transposed [k][row]
    __shared__ float s_lds[NB * 16];      // 4KB
    __shared__ float bonds_lds[NB * 16];  // 4KB
    __shared__ float agg_lds[NB * 17];    // padded stride 17
    __shared__ float wn_lds[16 * 128];    // 8KB
    __shared__ float wi_lds[16 * 128];    // 8KB

    const int tid = threadIdx.x;
    const int nb  = blockIdx.x * NB;

    // ---- persistent staging: S, bonds, Wn, Wi -----------------------------
    {
        int row = tid >> 2;
        int j4  = (tid & 3) * 4;
        int n   = nb + row;
        float4 sv = f4zero(), bv = f4zero();
        if (n < N) {
            sv = *(const float4*)(S + n * BD + j4);
            bv = *(const float4*)(bonds + n * BD + j4);
        }
        *(float4*)(s_lds + row * 16 + j4)     = sv;
        *(float4*)(bonds_lds + row * 16 + j4) = bv;
#pragma unroll
        for (int p = 0; p < 2; ++p) {
            int idx = tid + 256 * p;
            int r2  = idx >> 5;
            int h4  = (idx & 31) * 4;
            *(float4*)(wn_lds + r2 * 128 + h4) = *(const float4*)(Wn + r2 * 128 + h4);
            *(float4*)(wi_lds + r2 * 128 + h4) = *(const float4*)(Wi + r2 * 128 + h4);
        }
    }

    const int rg = tid >> 5;   // 0..7  -> rows rg*8 .. rg*8+7
    const int cq = tid & 31;   // 0..31 -> float4 cols cq and cq+32

    float4 acc[8][2];
#pragma unroll
    for (int i = 0; i < 8; ++i) { acc[i][0] = f4zero(); acc[i][1] = f4zero(); }

    float4 bias_v0 = *(const float4*)(bias + cq * 4);
    float4 bias_v1 = *(const float4*)(bias + cq * 4 + 128);

    // ---- GEMM: A = atoms @ kmat, K-chunks of 16 ---------------------------
    const int ld_row = tid >> 2;         // staging helpers
    const int ld_k4  = (tid & 3) * 4;

    for (int kk = 0; kk < AD; kk += 16) {
        // load to registers first
        float4 areg = f4zero();
        {
            int n = nb + ld_row;
            if (n < N) areg = *(const float4*)(atoms + (size_t)n * AD + kk + ld_k4);
        }
        float4 kreg[4];
#pragma unroll
        for (int p = 0; p < 4; ++p) {
            int idx  = tid + 256 * p;
            int krow = idx >> 6;
            int kc4  = (idx & 63) * 4;
            kreg[p] = *(const float4*)(kmat + (size_t)(kk + krow) * BD2 + kc4);
        }
        __syncthreads();   // previous chunk fully consumed
        // atoms transposed: atoms_t[k][row]
        atoms_t[(ld_k4 + 0) * 64 + ld_row] = areg.x;
        atoms_t[(ld_k4 + 1) * 64 + ld_row] = areg.y;
        atoms_t[(ld_k4 + 2) * 64 + ld_row] = areg.z;
        atoms_t[(ld_k4 + 3) * 64 + ld_row] = areg.w;
#pragma unroll
        for (int p = 0; p < 4; ++p) {
            int idx  = tid + 256 * p;
            int krow = idx >> 6;
            int kc4  = (idx & 63) * 4;
            *(float4*)(k_lds + krow * 256 + kc4) = kreg[p];
        }
        __syncthreads();

#pragma unroll
        for (int k = 0; k < 16; ++k) {
            float4 a0 = *(const float4*)(atoms_t + k * 64 + rg * 8);
            float4 a1 = *(const float4*)(atoms_t + k * 64 + rg * 8 + 4);
            float4 kv0 = *(const float4*)(k_lds + k * 256 + cq * 4);
            float4 kv1 = *(const float4*)(k_lds + k * 256 + cq * 4 + 128);
            float a[8] = {a0.x, a0.y, a0.z, a0.w, a1.x, a1.y, a1.z, a1.w};
#pragma unroll
            for (int i = 0; i < 8; ++i) {
                acc[i][0].x = fmaf(a[i], kv0.x, acc[i][0].x);
                acc[i][0].y = fmaf(a[i], kv0.y, acc[i][0].y);
                acc[i][0].z = fmaf(a[i], kv0.z, acc[i][0].z);
                acc[i][0].w = fmaf(a[i], kv0.w, acc[i][0].w);
                acc[i][1].x = fmaf(a[i], kv1.x, acc[i][1].x);
                acc[i][1].y = fmaf(a[i], kv1.y, acc[i][1].y);
                acc[i][1].z = fmaf(a[i], kv1.z, acc[i][1].z);
                acc[i][1].w = fmaf(a[i], kv1.w, acc[i][1].w);
            }
        }
    }

    // ---- bias + contract with S, reduce across 4 j-groups via shfl --------
    // thread's columns: col = cq*4 + q*128 + m  -> i = q*8 + (cq>>2), j = (cq&3)*4 + m
    {
        const int jg = (cq & 3) * 4;
        const int ibase = cq >> 2;
#pragma unroll
        for (int r = 0; r < 8; ++r) {
            int row = rg * 8 + r;
            float4 sv = *(const float4*)(s_lds + row * 16 + jg);
#pragma unroll
            for (int q = 0; q < 2; ++q) {
                float4 av = acc[r][q];
                float4 bvq = (q == 0) ? bias_v0 : bias_v1;
                av.x += bvq.x; av.y += bvq.y; av.z += bvq.z; av.w += bvq.w;
                float p = av.x * sv.x + av.y * sv.y + av.z * sv.z + av.w * sv.w;
                p += __shfl_xor(p, 1);
                p += __shfl_xor(p, 2);
                if ((tid & 3) == 0) {
                    agg_lds[row * 17 + q * 8 + ibase] = p;
                }
            }
        }
    }
    __syncthreads();

    // ---- epilogue: out = relu(agg@Wn + relu(bonds@Wi)), 4 copies ----------
    {
        const int r  = tid >> 2;   // node row 0..63
        const int hg = tid & 3;
        const int n  = nb + r;
        float aggv[16], bv[16];
#pragma unroll
        for (int i = 0; i < 16; ++i) {
            aggv[i] = agg_lds[r * 17 + i];
            bv[i]   = bonds_lds[r * 16 + i];
        }
        if (n < N) {
#pragma unroll
            for (int hv = 0; hv < 8; ++hv) {
                int h = (hv * 4 + hg) * 4;
                float4 nv = f4zero(), ev = f4zero();
#pragma unroll
                for (int i = 0; i < 16; ++i) {
                    float4 w  = *(const float4*)(wn_lds + i * 128 + h);
                    float4 w2 = *(const float4*)(wi_lds + i * 128 + h);
                    nv.x = fmaf(aggv[i], w.x, nv.x);
                    nv.y = fmaf(aggv[i], w.y, nv.y);
                    nv.z = fmaf(aggv[i], w.z, nv.z);
                    nv.w = fmaf(aggv[i], w.w, nv.w);
                    ev.x = fmaf(bv[i], w2.x, ev.x);
                    ev.y = fmaf(bv[i], w2.y, ev.y);
                    ev.z = fmaf(bv[i], w2.z, ev.z);
                    ev.w = fmaf(bv[i], w2.w, ev.w);
                }
                ev.x = fmaxf(ev.x, 0.f); ev.y = fmaxf(ev.y, 0.f);
                ev.z = fmaxf(ev.z, 0.f); ev.w = fmaxf(ev.w, 0.f);
                float4 rv;
                rv.x = fmaxf(nv.x + ev.x, 0.f);
                rv.y = fmaxf(nv.y + ev.y, 0.f);
                rv.z = fmaxf(nv.z + ev.z, 0.f);
                rv.w = fmaxf(nv.w + ev.w, 0.f);
#pragma unroll
                for (int s = 0; s < 4; ++s) {
                    *(float4*)(out + ((size_t)s * N + n) * HIDDEN + h) = rv;
                }
            }
        }
    }
}

// ---------------------------------------------------------------------------
extern "C" void kernel_launch(void* const* d_in, const int* in_sizes, int n_in,
                              void* d_out, int out_size, void* d_ws, size_t ws_size,
                              hipStream_t stream)
{
    const float* atoms = (const float*)d_in[0];
    const float* bonds = (const float*)d_in[1];
    const int2*  pairs = (const int2*)d_in[2];
    const float* kmat  = (const float*)d_in[3];
    const float* bias  = (const float*)d_in[4];
    const float* Wn    = (const float*)d_in[5];
    const float* Wi    = (const float*)d_in[6];
    float* out = (float*)d_out;
    float* S   = (float*)d_ws;   // N x 16

    hipMemsetAsync(S, 0, (size_t)N * BD * sizeof(float), stream);

    const int groups = (NE + EPG - 1) / EPG;          // 16-lane groups
    const int threads = groups * 16;
    edge_scatter_sorted<<<(threads + 255) / 256, 256, 0, stream>>>(pairs, bonds, S);

    fused_node<<<(N + NB - 1) / NB, 256, 0, stream>>>(
        atoms, bonds, kmat, bias, Wn, Wi, S, out);
}

// Round 3
// 78.532 us; speedup vs baseline: 3.1740x; 1.5180x over previous
//
#include <hip/hip_runtime.h>

typedef __attribute__((ext_vector_type(8))) short bf16x8;
typedef __attribute__((ext_vector_type(4))) float f32x4;

constexpr int N       = 50000;
constexpr int NE      = 800000;
constexpr int AD      = 128;   // ATOM_DIM
constexpr int BD      = 16;    // BOND_DIM
constexpr int BD2     = 256;   // BD*BD
constexpr int HIDDEN  = 128;
constexpr int EPG     = 32;    // edges per 16-lane group (NE % 32 == 0)
constexpr int NB      = 64;    // nodes per block in fused kernel

// f32 -> bf16 round-to-nearest-even
__device__ inline short f2bf(float f) {
    union U { float f; unsigned u; } v; v.f = f;
    unsigned r = v.u + 0x7fffu + ((v.u >> 16) & 1u);
    return (short)(r >> 16);
}

// ---------------------------------------------------------------------------
// Kernel 0: convert kmat (128x256 f32, row-major [k][col]) into bf16
// MFMA-B-fragment-linear layout:
//   kbf[u=nf*4+kk][lane][j] = kmat[kk*32 + (lane>>4)*8 + j][nf*16 + (lane&15)]
// so a wave's B-fragment for (nf,kk) is one coalesced 16B/lane read.
// ---------------------------------------------------------------------------
__global__ __launch_bounds__(256) void prep_kbf(
    const float* __restrict__ kmat, short* __restrict__ kbf)
{
    int t = blockIdx.x * 256 + threadIdx.x;   // 0..4095
    int u = t >> 6, l = t & 63;
    int nf = u >> 2, kk = u & 3;
    int col = nf * 16 + (l & 15);
    int k0  = kk * 32 + (l >> 4) * 8;
    bf16x8 o;
#pragma unroll
    for (int j = 0; j < 8; ++j) o[j] = f2bf(kmat[(size_t)(k0 + j) * BD2 + col]);
    *(bf16x8*)(kbf + (size_t)t * 8) = o;
}

// ---------------------------------------------------------------------------
// Kernel 1: S[s] = sum over edges with src==s of bonds[nbr]
// sorted by src -> run-length segmented reduction, unroll-4 prefetch so 4
// bonds gathers are in flight per chunk (breaks the serial latency chain).
// ---------------------------------------------------------------------------
__global__ __launch_bounds__(256) void edge_scatter_sorted(
    const int2* __restrict__ pairs,
    const float* __restrict__ bonds,
    float* __restrict__ S)
{
    const int gid = (int)((blockIdx.x * (unsigned)blockDim.x + threadIdx.x) >> 4);
    const int c   = threadIdx.x & 15;
    long e0 = (long)gid * EPG;
    if (e0 >= NE) return;

    int   cur = -1;
    float acc = 0.f;
    for (long e = e0; e < e0 + EPG; e += 4) {
        int2 pb[4]; float vb[4];
#pragma unroll
        for (int i = 0; i < 4; ++i) pb[i] = pairs[e + i];
#pragma unroll
        for (int i = 0; i < 4; ++i) vb[i] = bonds[(size_t)pb[i].y * BD + c];
#pragma unroll
        for (int i = 0; i < 4; ++i) {
            if (pb[i].x != cur) {
                if (cur >= 0) atomicAdd(&S[(size_t)cur * BD + c], acc);
                acc = 0.f;
                cur = pb[i].x;
            }
            acc += vb[i];
        }
    }
    atomicAdd(&S[(size_t)cur * BD + c], acc);
}

// ---------------------------------------------------------------------------
// Kernel 2: fused per-node pipeline with bf16 MFMA GEMM.
// 256 threads = 4 waves, 64 nodes/block, 16 nodes/wave.
//  A[n] = atoms@kmat + bias  via mfma_f32_16x16x32_bf16 (16 nf x 4 kk)
//  agg[n][i] = sum_j (A+bias)[n][i*16+j] * S[n][j]  in-register via shfl
//  out = relu(agg@Wn + relu(bonds@Wi)), written 4x  (VALU epilogue)
// ---------------------------------------------------------------------------
__global__ __launch_bounds__(256, 3) void fused_node_mfma(
    const float* __restrict__ atoms,
    const float* __restrict__ bonds,
    const short* __restrict__ kbf,    // 64KB bf16 fragment-linear kmat
    const float* __restrict__ bias,   // 256
    const float* __restrict__ Wn,     // 16 x 128
    const float* __restrict__ Wi,     // 16 x 128
    const float* __restrict__ S,      // N x 16
    float* __restrict__ out)          // 4 x N x 128
{
    __shared__ float wn_lds[16 * 128];     // 8KB
    __shared__ float wi_lds[16 * 128];     // 8KB
    __shared__ float bonds_lds[NB * 20];   // 5KB, stride 20 (bank-friendly)
    __shared__ float agg_lds[NB * 17];     // 4.25KB, stride 17 (conflict-free)

    const int tid = threadIdx.x;
    const int nb  = blockIdx.x * NB;

    // ---- stage Wn, Wi, bonds (consumed after the single barrier) ----------
    {
#pragma unroll
        for (int p = 0; p < 2; ++p) {
            int i4 = (tid + 256 * p) * 4;
            *(float4*)(wn_lds + i4) = *(const float4*)(Wn + i4);
            *(float4*)(wi_lds + i4) = *(const float4*)(Wi + i4);
        }
        int row = tid >> 2, j4 = (tid & 3) * 4;
        int n = nb + row; if (n >= N) n = N - 1;
        *(float4*)(bonds_lds + row * 20 + j4) = *(const float4*)(bonds + (size_t)n * BD + j4);
    }

    const int w  = tid >> 6;    // wave 0..3
    const int l  = tid & 63;
    const int lq = l >> 4;      // quarter 0..3
    const int lj = l & 15;
    const int wrow = nb + w * 16;

    // ---- A fragments: atoms rows in bf16, k contiguous per lane -----------
    int arow = wrow + lj; if (arow >= N) arow = N - 1;
    const float* ap = atoms + (size_t)arow * AD + lq * 8;
    bf16x8 afrag[4];
#pragma unroll
    for (int kk = 0; kk < 4; ++kk) {
        float4 a0 = *(const float4*)(ap + kk * 32);
        float4 a1 = *(const float4*)(ap + kk * 32 + 4);
        bf16x8 af;
        af[0] = f2bf(a0.x); af[1] = f2bf(a0.y); af[2] = f2bf(a0.z); af[3] = f2bf(a0.w);
        af[4] = f2bf(a1.x); af[5] = f2bf(a1.y); af[6] = f2bf(a1.z); af[7] = f2bf(a1.w);
        afrag[kk] = af;
    }

    // ---- MFMA GEMM: acc[nf] = sum_kk A(kk) x B(nf,kk) ---------------------
    f32x4 acc[16];
#pragma unroll
    for (int nf = 0; nf < 16; ++nf) acc[nf] = (f32x4){0.f, 0.f, 0.f, 0.f};

    const bf16x8* kb = (const bf16x8*)kbf;
#pragma unroll 1
    for (int kk = 0; kk < 4; ++kk) {
#pragma unroll
        for (int nf = 0; nf < 16; ++nf) {
            bf16x8 b = kb[(size_t)(nf * 4 + kk) * 64 + l];
            acc[nf] = __builtin_amdgcn_mfma_f32_16x16x32_bf16(afrag[kk], b, acc[nf], 0, 0, 0);
        }
    }

    // ---- contract with S: agg[row][i] = sum_j (C+bias)[row][i*16+j]*S[row][j]
    // C/D layout: col = nf*16 + lj, row = wrow + 4*lq + r
    float sval[4];
#pragma unroll
    for (int r = 0; r < 4; ++r) {
        int n = wrow + 4 * lq + r; if (n >= N) n = N - 1;
        sval[r] = S[(size_t)n * BD + lj];
    }
    float aggv[4];
#pragma unroll
    for (int nf = 0; nf < 16; ++nf) {
        float bv = bias[nf * 16 + lj];
#pragma unroll
        for (int r = 0; r < 4; ++r) {
            float p = (acc[nf][r] + bv) * sval[r];
            p += __shfl_xor(p, 1);
            p += __shfl_xor(p, 2);
            p += __shfl_xor(p, 4);
            p += __shfl_xor(p, 8);
            if (lj == nf) aggv[r] = p;   // lane lj keeps i == lj
        }
    }
#pragma unroll
    for (int r = 0; r < 4; ++r)
        agg_lds[(w * 16 + 4 * lq + r) * 17 + lj] = aggv[r];

    __syncthreads();   // the only barrier

    // ---- epilogue: out = relu(agg@Wn + relu(bonds@Wi)), 4 copies ----------
    {
        const int r2 = tid >> 2;   // node 0..63
        const int hg = tid & 3;
        const int n2 = nb + r2;
        float aggr[16], bvr[16];
#pragma unroll
        for (int i = 0; i < 16; ++i) {
            aggr[i] = agg_lds[r2 * 17 + i];
            bvr[i]  = bonds_lds[r2 * 20 + i];
        }
        if (n2 < N) {
#pragma unroll
            for (int hv = 0; hv < 8; ++hv) {
                int h = (hv * 4 + hg) * 4;
                float4 nv = make_float4(0.f, 0.f, 0.f, 0.f);
                float4 ev = make_float4(0.f, 0.f, 0.f, 0.f);
#pragma unroll
                for (int i = 0; i < 16; ++i) {
                    float4 wv  = *(const float4*)(wn_lds + i * 128 + h);
                    float4 wv2 = *(const float4*)(wi_lds + i * 128 + h);
                    nv.x = fmaf(aggr[i], wv.x, nv.x);
                    nv.y = fmaf(aggr[i], wv.y, nv.y);
                    nv.z = fmaf(aggr[i], wv.z, nv.z);
                    nv.w = fmaf(aggr[i], wv.w, nv.w);
                    ev.x = fmaf(bvr[i], wv2.x, ev.x);
                    ev.y = fmaf(bvr[i], wv2.y, ev.y);
                    ev.z = fmaf(bvr[i], wv2.z, ev.z);
                    ev.w = fmaf(bvr[i], wv2.w, ev.w);
                }
                ev.x = fmaxf(ev.x, 0.f); ev.y = fmaxf(ev.y, 0.f);
                ev.z = fmaxf(ev.z, 0.f); ev.w = fmaxf(ev.w, 0.f);
                float4 rv;
                rv.x = fmaxf(nv.x + ev.x, 0.f);
                rv.y = fmaxf(nv.y + ev.y, 0.f);
                rv.z = fmaxf(nv.z + ev.z, 0.f);
                rv.w = fmaxf(nv.w + ev.w, 0.f);
#pragma unroll
                for (int s = 0; s < 4; ++s) {
                    *(float4*)(out + ((size_t)s * N + n2) * HIDDEN + h) = rv;
                }
            }
        }
    }
}

// ---------------------------------------------------------------------------
extern "C" void kernel_launch(void* const* d_in, const int* in_sizes, int n_in,
                              void* d_out, int out_size, void* d_ws, size_t ws_size,
                              hipStream_t stream)
{
    const float* atoms = (const float*)d_in[0];
    const float* bonds = (const float*)d_in[1];
    const int2*  pairs = (const int2*)d_in[2];
    const float* kmat  = (const float*)d_in[3];
    const float* bias  = (const float*)d_in[4];
    const float* Wn    = (const float*)d_in[5];
    const float* Wi    = (const float*)d_in[6];
    float* out = (float*)d_out;

    float* S   = (float*)d_ws;                                  // N*16 f32 = 3.2MB
    short* kbf = (short*)((char*)d_ws + (size_t)N * BD * 4);    // 64KB bf16

    hipMemsetAsync(S, 0, (size_t)N * BD * sizeof(float), stream);
    prep_kbf<<<16, 256, 0, stream>>>(kmat, kbf);

    const int groups  = NE / EPG;            // 25000 16-lane groups
    const int threads = groups * 16;
    edge_scatter_sorted<<<(threads + 255) / 256, 256, 0, stream>>>(pairs, bonds, S);

    fused_node_mfma<<<(N + NB - 1) / NB, 256, 0, stream>>>(
        atoms, bonds, kbf, bias, Wn, Wi, S, out);
}

// Round 4
// 71.913 us; speedup vs baseline: 3.4662x; 1.0920x over previous
//
#include <hip/hip_runtime.h>

typedef __attribute__((ext_vector_type(8))) short bf16x8;
typedef __attribute__((ext_vector_type(4))) float f32x4;

constexpr int N       = 50000;
constexpr int NE      = 800000;
constexpr int AD      = 128;   // ATOM_DIM
constexpr int BD      = 16;    // BOND_DIM
constexpr int BD2     = 256;   // BD*BD
constexpr int HIDDEN  = 128;
constexpr int EPG     = 32;    // edges per 16-lane group (NE % 32 == 0)
constexpr int NB      = 64;    // nodes per block in fused kernel

// f32 -> bf16 round-to-nearest-even
__device__ inline short f2bf(float f) {
    union U { float f; unsigned u; } v; v.f = f;
    unsigned r = v.u + 0x7fffu + ((v.u >> 16) & 1u);
    return (short)(r >> 16);
}

// ---------------------------------------------------------------------------
// Kernel 0: build bf16 fragment-linear operand tables.
//  kbf  (64KB): kbf[u=nf*4+kk][lane][j] = kmat[kk*32+(l>>4)*8+j][nf*16+(l&15)]
//  wbf  (16KB): wbf[m*8+nf2][lane][j]   = W[k][nf2*16+(l&15)], k=(l>>4)*8+j,
//               zero for k>=16 (K padded 16->32). m=0: Wn, m=1: Wi.
// ---------------------------------------------------------------------------
__global__ __launch_bounds__(256) void prep_frags(
    const float* __restrict__ kmat,
    const float* __restrict__ Wn,
    const float* __restrict__ Wi,
    short* __restrict__ kbf,
    short* __restrict__ wbf)
{
    int t = blockIdx.x * 256 + threadIdx.x;
    if (t < 4096) {
        int u = t >> 6, l = t & 63;
        int nf = u >> 2, kk = u & 3;
        int col = nf * 16 + (l & 15);
        int k0  = kk * 32 + (l >> 4) * 8;
        bf16x8 o;
#pragma unroll
        for (int j = 0; j < 8; ++j) o[j] = f2bf(kmat[(size_t)(k0 + j) * BD2 + col]);
        *(bf16x8*)(kbf + (size_t)t * 8) = o;
    } else if (t < 4096 + 1024) {
        int t2 = t - 4096;
        int u = t2 >> 6, l = t2 & 63;
        int m = u >> 3, nf2 = u & 7;
        const float* W = m ? Wi : Wn;
        int col = nf2 * 16 + (l & 15);
        int k0  = (l >> 4) * 8;
        bf16x8 o;
#pragma unroll
        for (int j = 0; j < 8; ++j) {
            int k = k0 + j;
            o[j] = (k < 16) ? f2bf(W[(size_t)k * HIDDEN + col]) : (short)0;
        }
        *(bf16x8*)(wbf + (size_t)t2 * 8) = o;
    }
}

// ---------------------------------------------------------------------------
// Kernel 1: S[s] = sum over edges with src==s of bonds[nbr]
// sorted by src -> run-length segmented reduction, unroll-4 prefetch.
// ---------------------------------------------------------------------------
__global__ __launch_bounds__(256) void edge_scatter_sorted(
    const int2* __restrict__ pairs,
    const float* __restrict__ bonds,
    float* __restrict__ S)
{
    const int gid = (int)((blockIdx.x * (unsigned)blockDim.x + threadIdx.x) >> 4);
    const int c   = threadIdx.x & 15;
    long e0 = (long)gid * EPG;
    if (e0 >= NE) return;

    int   cur = -1;
    float acc = 0.f;
    for (long e = e0; e < e0 + EPG; e += 4) {
        int2 pb[4]; float vb[4];
#pragma unroll
        for (int i = 0; i < 4; ++i) pb[i] = pairs[e + i];
#pragma unroll
        for (int i = 0; i < 4; ++i) vb[i] = bonds[(size_t)pb[i].y * BD + c];
#pragma unroll
        for (int i = 0; i < 4; ++i) {
            if (pb[i].x != cur) {
                if (cur >= 0) atomicAdd(&S[(size_t)cur * BD + c], acc);
                acc = 0.f;
                cur = pb[i].x;
            }
            acc += vb[i];
        }
    }
    atomicAdd(&S[(size_t)cur * BD + c], acc);
}

// ---------------------------------------------------------------------------
// Kernel 2: fully-register fused per-node pipeline (0 LDS, no barrier).
// 4 waves/block, 16 nodes/wave.
//  Main GEMM (swapped operands): acc[nf] = D[c=nf*16+4lq+r][node=lj]
//  Contraction: lane-local fmas + 2 shfl_xor -> every lane holds agg[lj][0..15]
//  Epilogue:   E = mfma(bonds_frag, Wi_frag, 0); out = mfma(agg, Wn, relu(E))
// ---------------------------------------------------------------------------
__global__ __launch_bounds__(256, 3) void fused_node_mfma(
    const float* __restrict__ atoms,
    const float* __restrict__ bonds,
    const short* __restrict__ kbf,    // 64KB fragment-linear kmat
    const short* __restrict__ wbf,    // 16KB fragment-linear Wn|Wi
    const float* __restrict__ bias,   // 256
    const float* __restrict__ S,      // N x 16
    float* __restrict__ out)          // 4 x N x 128
{
    const int tid = threadIdx.x;
    const int w   = tid >> 6;
    const int l   = tid & 63;
    const int lq  = l >> 4;
    const int lj  = l & 15;
    const int wrow = blockIdx.x * NB + w * 16;

    // ---- A fragments: this wave's 16 atoms rows, bf16 ---------------------
    int arow = wrow + lj; if (arow >= N) arow = N - 1;
    const float* ap = atoms + (size_t)arow * AD + lq * 8;
    bf16x8 afrag[4];
#pragma unroll
    for (int kk = 0; kk < 4; ++kk) {
        float4 a0 = *(const float4*)(ap + kk * 32);
        float4 a1 = *(const float4*)(ap + kk * 32 + 4);
        bf16x8 af;
        af[0] = f2bf(a0.x); af[1] = f2bf(a0.y); af[2] = f2bf(a0.z); af[3] = f2bf(a0.w);
        af[4] = f2bf(a1.x); af[5] = f2bf(a1.y); af[6] = f2bf(a1.z); af[7] = f2bf(a1.w);
        afrag[kk] = af;
    }

    // ---- main GEMM, swapped operands: D = kmat^T x atoms^T ----------------
    f32x4 acc[16];
#pragma unroll
    for (int nf = 0; nf < 16; ++nf) acc[nf] = (f32x4){0.f, 0.f, 0.f, 0.f};

    const bf16x8* kb = (const bf16x8*)kbf;
#pragma unroll 1
    for (int kk = 0; kk < 4; ++kk) {
#pragma unroll
        for (int nf = 0; nf < 16; ++nf) {
            bf16x8 b = kb[(size_t)(nf * 4 + kk) * 64 + l];
            acc[nf] = __builtin_amdgcn_mfma_f32_16x16x32_bf16(b, afrag[kk], acc[nf], 0, 0, 0);
        }
    }

    // ---- contraction with S: agg[lj][nf] = sum_j (A+bias)[lj][nf*16+j]*S[lj][j]
    // lane holds j = 4*lq + r (r=0..3); reduce over lq via 2 shfls.
    int srow = wrow + lj; if (srow >= N) srow = N - 1;
    float4 sv = *(const float4*)(S + (size_t)srow * BD + lq * 4);

    float aggf[16];
#pragma unroll
    for (int nf = 0; nf < 16; ++nf) {
        float4 bv = *(const float4*)(bias + nf * 16 + lq * 4);
        float q = (acc[nf][0] + bv.x) * sv.x
                + (acc[nf][1] + bv.y) * sv.y
                + (acc[nf][2] + bv.z) * sv.z
                + (acc[nf][3] + bv.w) * sv.w;
        q += __shfl_xor(q, 16);
        q += __shfl_xor(q, 32);
        aggf[nf] = q;          // every lane: agg for node lj, col nf
    }

    // ---- epilogue fragments (K=16 zero-padded to 32) ----------------------
    bf16x8 agg_a = (bf16x8){0,0,0,0,0,0,0,0};
    bf16x8 bond_a = (bf16x8){0,0,0,0,0,0,0,0};
    if (lq < 2) {
#pragma unroll
        for (int j = 0; j < 8; ++j) agg_a[j] = f2bf(aggf[lq * 8 + j]);
        int brow = wrow + lj; if (brow >= N) brow = N - 1;
        float4 b0 = *(const float4*)(bonds + (size_t)brow * BD + lq * 8);
        float4 b1 = *(const float4*)(bonds + (size_t)brow * BD + lq * 8 + 4);
        bond_a[0] = f2bf(b0.x); bond_a[1] = f2bf(b0.y); bond_a[2] = f2bf(b0.z); bond_a[3] = f2bf(b0.w);
        bond_a[4] = f2bf(b1.x); bond_a[5] = f2bf(b1.y); bond_a[6] = f2bf(b1.z); bond_a[7] = f2bf(b1.w);
    }

    // ---- epilogue MFMAs + store -------------------------------------------
    const bf16x8* wb = (const bf16x8*)wbf;
#pragma unroll
    for (int nf2 = 0; nf2 < 8; ++nf2) {
        bf16x8 wn_f = wb[(size_t)nf2 * 64 + l];
        bf16x8 wi_f = wb[(size_t)(8 + nf2) * 64 + l];
        f32x4 e = __builtin_amdgcn_mfma_f32_16x16x32_bf16(
            bond_a, wi_f, (f32x4){0.f, 0.f, 0.f, 0.f}, 0, 0, 0);
        e[0] = fmaxf(e[0], 0.f); e[1] = fmaxf(e[1], 0.f);
        e[2] = fmaxf(e[2], 0.f); e[3] = fmaxf(e[3], 0.f);
        f32x4 o = __builtin_amdgcn_mfma_f32_16x16x32_bf16(agg_a, wn_f, e, 0, 0, 0);
#pragma unroll
        for (int r = 0; r < 4; ++r) {
            int node = wrow + 4 * lq + r;
            if (node < N) {
                float v = fmaxf(o[r], 0.f);
                size_t base = (size_t)node * HIDDEN + nf2 * 16 + lj;
#pragma unroll
                for (int s = 0; s < 4; ++s)
                    out[base + (size_t)s * N * HIDDEN] = v;
            }
        }
    }
}

// ---------------------------------------------------------------------------
extern "C" void kernel_launch(void* const* d_in, const int* in_sizes, int n_in,
                              void* d_out, int out_size, void* d_ws, size_t ws_size,
                              hipStream_t stream)
{
    const float* atoms = (const float*)d_in[0];
    const float* bonds = (const float*)d_in[1];
    const int2*  pairs = (const int2*)d_in[2];
    const float* kmat  = (const float*)d_in[3];
    const float* bias  = (const float*)d_in[4];
    const float* Wn    = (const float*)d_in[5];
    const float* Wi    = (const float*)d_in[6];
    float* out = (float*)d_out;

    float* S   = (float*)d_ws;                                   // 3.2MB
    short* kbf = (short*)((char*)d_ws + (size_t)N * BD * 4);     // 64KB
    short* wbf = kbf + 4096 * 8;                                 // 16KB

    hipMemsetAsync(S, 0, (size_t)N * BD * sizeof(float), stream);
    prep_frags<<<20, 256, 0, stream>>>(kmat, Wn, Wi, kbf, wbf);

    const int groups  = NE / EPG;
    const int threads = groups * 16;
    edge_scatter_sorted<<<(threads + 255) / 256, 256, 0, stream>>>(pairs, bonds, S);

    fused_node_mfma<<<(N + NB - 1) / NB, 256, 0, stream>>>(
        atoms, bonds, kbf, wbf, bias, S, out);
}